// Round 9
// baseline (144.808 us; speedup 1.0000x reference)
//
#include <hip/hip_runtime.h>
#include <stdint.h>

#define DEV static __device__ __forceinline__

typedef __attribute__((ext_vector_type(8))) __bf16 bfx8;
typedef __attribute__((ext_vector_type(4))) float f32x4;

DEV short f2bfbits(float f) {
  union { float f; unsigned u; } v; v.f = f;
  unsigned r = v.u + 0x7fffu + ((v.u >> 16) & 1u);
  return (short)(r >> 16);
}

DEV void gload_lds16(const void* g, void* lds) {
  __builtin_amdgcn_global_load_lds(
      (const __attribute__((address_space(1))) void*)g,
      (__attribute__((address_space(3))) void*)lds, 16, 0, 0);
}

// ---------------- prep (merged): x->bf16 | mask | both weight transposes ----------------
__global__ void k_prep(const float* __restrict__ x, short* __restrict__ xb,
                       const int* __restrict__ mask, unsigned char* __restrict__ msk,
                       const float* __restrict__ Wqkv, short* __restrict__ wqkvT,
                       const float* __restrict__ Wout, short* __restrict__ woutT) {
  __shared__ float tile[32][33];
  int bx = blockIdx.x;
  int t = threadIdx.x;
  if (bx < 4096) {
    int i = bx * 256 + t;                            // 4 floats per thread
    float4 v = ((const float4*)x)[i];
    union { short s[4]; uint64_t u; } o;
    o.s[0] = f2bfbits(v.x); o.s[1] = f2bfbits(v.y);
    o.s[2] = f2bfbits(v.z); o.s[3] = f2bfbits(v.w);
    ((uint64_t*)xb)[i] = o.u;
  } else if (bx < 4112) {
    int i = (bx - 4096) * 256 + t;                   // [0, 4096)
    int b = i >> 10, n = i & 1023;
    msk[i] = (n == 0) ? (unsigned char)1 : (unsigned char)(mask[b * 1023 + n - 1] != 0);
  } else {
    int tb = bx - 4112;                              // 4096 transpose blocks
    int bxx = tb & 127, byy = tb >> 7;
    const float* src; short* dst; int C;
    if (bxx < 96) { src = Wqkv; dst = wqkvT; C = 3072; }
    else          { src = Wout; dst = woutT; C = 1024; bxx -= 96; }
    const int R = 1024;
    int c0 = bxx * 32, r0 = byy * 32;
    int tx = t & 31, ty = t >> 5;                    // (32,8)
    #pragma unroll
    for (int j = 0; j < 32; j += 8)
      tile[ty + j][tx] = src[(size_t)(r0 + ty + j) * C + c0 + tx];
    __syncthreads();
    #pragma unroll
    for (int j = 0; j < 32; j += 8)
      dst[(size_t)(c0 + ty + j) * R + r0 + tx] = f2bfbits(tile[tx][ty + j]);
  }
}

// ---------------- QKV GEMM: BK=64 (2 x BK32 sub-steps per barrier pair) ----------------
//   q/kfrag: [bh][blk=n>>4][half=d>>5][lane=((d>>3)&3)*16+(n&15)][8]   (2KB per blk)
//   vfrag:   [bh][db=d>>4][jj=n>>5][lane=((n>>3)&3)*16+(d&15)][8]      (1KB per jj)
__global__ __launch_bounds__(256)
void k_gemm(const short* __restrict__ A, const short* __restrict__ Bt,
            const float* __restrict__ bias, int K,
            short* __restrict__ qf, short* __restrict__ kf,
            short* __restrict__ vf) {
  __shared__ short smem[16384];       // 32KB: As[2][4096] | Bs[2][4096]; epilogue image
  short* As = smem;
  short* Bs = smem + 8192;
  const int t = threadIdx.x;
  const int l = t & 63, w = t >> 6;
  const int lr = l & 15, lk = l >> 4;
  const int m0 = blockIdx.y * 128, n0 = blockIdx.x * 128;
  const int wr = (w >> 1) * 64, wc = (w & 1) * 64;
  f32x4 acc[4][4] = {};

  const int srow = t >> 2;
  const int sc8 = (t & 3) * 8;
  const size_t aoff1 = (size_t)(m0 + srow) * K + sc8;
  const size_t aoff2 = (size_t)(m0 + srow + 64) * K + sc8;
  const size_t boff1 = (size_t)(n0 + srow) * K + sc8;
  const size_t boff2 = (size_t)(n0 + srow + 64) * K + sc8;
  const int ldst = (t & ~63) * 8;     // wave-linear LDS dest base (shorts)

  for (int k0 = 0; k0 < K; k0 += 64) {
    #pragma unroll
    for (int s = 0; s < 2; s++) {
      int kc = k0 + s * 32;
      gload_lds16(A + aoff1 + kc, As + s * 4096 + ldst);
      gload_lds16(A + aoff2 + kc, As + s * 4096 + ldst + 2048);
      gload_lds16(Bt + boff1 + kc, Bs + s * 4096 + ldst);
      gload_lds16(Bt + boff2 + kc, Bs + s * 4096 + ldst + 2048);
    }
    __syncthreads();
    #pragma unroll
    for (int s = 0; s < 2; s++) {
      bfx8 af[4], bf[4];
      #pragma unroll
      for (int m = 0; m < 4; m++)
        af[m] = *(const bfx8*)&As[s * 4096 + (wr + m * 16 + lr) * 32 + lk * 8];
      #pragma unroll
      for (int n = 0; n < 4; n++)
        bf[n] = *(const bfx8*)&Bs[s * 4096 + (wc + n * 16 + lr) * 32 + lk * 8];
      #pragma unroll
      for (int m = 0; m < 4; m++)
        #pragma unroll
        for (int n = 0; n < 4; n++)
          acc[m][n] = __builtin_amdgcn_mfma_f32_16x16x32_bf16(af[m], bf[n], acc[m][n], 0, 0, 0);
    }
    __syncthreads();
  }

  // ---- epilogue: fragment-ordered LDS image, then coalesced stores ----
  const int which = n0 >> 10;                 // 0=q 1=k 2=v (tiles never straddle)
  const int head = w & 1;                     // head within the 128-col tile
  const int band = w >> 1;                    // row band (wr/64)
  const int bb = m0 >> 10;
  short* dstp = (which == 0) ? qf : (which == 1) ? kf : vf;

  #pragma unroll
  for (int p = 0; p < 2; p++) {
    #pragma unroll
    for (int mm = 0; mm < 2; mm++) {
      int m = 2 * p + mm;
      #pragma unroll
      for (int n = 0; n < 4; n++) {
        int gc = n0 + wc + n * 16 + lr;
        float bv = bias[gc];
        #pragma unroll
        for (int i = 0; i < 4; i++) {
          short val = f2bfbits(acc[m][n][i] + bv);
          int off;
          if (which < 2) {
            off = ((((band * 2 + head) * 2 + mm) * 2 + (n >> 1)) * 64 +
                   ((2 * n + (lr >> 3)) & 3) * 16 + 4 * lk + i) * 8 + (lr & 7);
          } else {
            off = (((band * 2 + head) * 4 + n) * 64 +
                   (2 * mm + ((4 * lk + i) >> 3)) * 16 + lr) * 8 + ((4 * lk + i) & 7);
          }
          smem[off] = val;
        }
      }
    }
    __syncthreads();
    if (which < 2) {
      #pragma unroll
      for (int r = 0; r < 4; r++) {
        int rb = r >> 1, rh = r & 1;
        int bh_r = bb * 16 + ((n0 & 1023) >> 6) + rh;
        int blk0 = ((m0 & 1023) >> 4) + 4 * rb + 2 * p;
        size_t g = ((size_t)(bh_r * 64 + blk0) << 10) + t * 8;
        *(int4*)&dstp[g] = *(const int4*)&smem[r * 2048 + t * 8];
      }
    } else {
      #pragma unroll
      for (int r = 0; r < 4; r++) {
        int rb = r >> 1, rh = r & 1;
        int bh_r = bb * 16 + ((n0 & 1023) >> 6) + rh;
        int jj = ((m0 & 1023) >> 5) + 2 * rb + p;
        int db = t >> 6;
        size_t g = (((size_t)(bh_r * 4 + db) * 32 + jj) << 9) + (t & 63) * 8;
        *(int4*)&dstp[g] = *(const int4*)&smem[r * 2048 + t * 8];
      }
    }
    if (p == 0) __syncthreads();
  }
}

// ---------------- out GEMM: BM=128, BN=64, BK=64 (2 sub-steps/barrier) ----------------
__global__ __launch_bounds__(256)
void k_gemm_out(const short* __restrict__ A, const short* __restrict__ Bt,
                const float* __restrict__ bias, float* __restrict__ outF) {
  __shared__ short As[2][4096];       // 16KB
  __shared__ short Bs[2][2048];       //  8KB
  const int K = 1024;
  const int t = threadIdx.x;
  const int l = t & 63, w = t >> 6;
  const int lr = l & 15, lk = l >> 4;
  const int m0 = blockIdx.y * 128, n0 = blockIdx.x * 64;
  const int wr = (w >> 1) * 64, wc = (w & 1) * 32;
  f32x4 acc[4][2] = {};

  const int srow = t >> 2;
  const int sc8 = (t & 3) * 8;
  const size_t aoff1 = (size_t)(m0 + srow) * K + sc8;
  const size_t aoff2 = (size_t)(m0 + srow + 64) * K + sc8;
  const size_t boff1 = (size_t)(n0 + srow) * K + sc8;
  const int ldst = (t & ~63) * 8;

  for (int k0 = 0; k0 < K; k0 += 64) {
    #pragma unroll
    for (int s = 0; s < 2; s++) {
      int kc = k0 + s * 32;
      gload_lds16(A + aoff1 + kc, &As[s][ldst]);
      gload_lds16(A + aoff2 + kc, &As[s][ldst + 2048]);
      gload_lds16(Bt + boff1 + kc, &Bs[s][ldst]);
    }
    __syncthreads();
    #pragma unroll
    for (int s = 0; s < 2; s++) {
      bfx8 af[4], bf[2];
      #pragma unroll
      for (int m = 0; m < 4; m++)
        af[m] = *(const bfx8*)&As[s][(wr + m * 16 + lr) * 32 + lk * 8];
      #pragma unroll
      for (int n = 0; n < 2; n++)
        bf[n] = *(const bfx8*)&Bs[s][(wc + n * 16 + lr) * 32 + lk * 8];
      #pragma unroll
      for (int m = 0; m < 4; m++)
        #pragma unroll
        for (int n = 0; n < 2; n++)
          acc[m][n] = __builtin_amdgcn_mfma_f32_16x16x32_bf16(af[m], bf[n], acc[m][n], 0, 0, 0);
    }
    __syncthreads();
  }

  #pragma unroll
  for (int m = 0; m < 4; m++) {
    #pragma unroll
    for (int n = 0; n < 2; n++) {
      int gc = n0 + wc + n * 16 + lr;
      float bv = bias[gc];
      #pragma unroll
      for (int i = 0; i < 4; i++) {
        int gr = m0 + wr + m * 16 + 4 * lk + i;
        outF[(size_t)gr * 1024 + gc] = acc[m][n][i] + bv;
      }
    }
  }
}

// ---------------- fused attention v6: QBLK=32, 2048 WGs (unchanged) ----------------
__global__ __launch_bounds__(512, 2)
void k_attn(const short* __restrict__ qf_, const short* __restrict__ kf_,
            const short* __restrict__ vf_, const unsigned char* __restrict__ msk,
            float* __restrict__ attn, short* __restrict__ ctx) {
  __shared__ short P[32 * 1024];      // 64KB bf16 P, swizzled 16B slots
  __shared__ float redM[32][8];
  __shared__ float redS[32][8];
  const int t = threadIdx.x, l = t & 63, w = t >> 6;
  const int lr = l & 15, lk = l >> 4;
  // XCD-chunked swizzle: 2048 WGs = 8 XCDs x 256; 32 consecutive = one (b,h)
  const int wg = ((blockIdx.x & 7) << 8) | (blockIdx.x >> 3);
  const int rt = wg & 31, h = (wg >> 5) & 15, b = wg >> 9;
  const int bh = b * 16 + h;
  const int r0 = rt * 32;
  const float NEG = -3.402823466e38f;

  // Q fragments: blocks rt*2, rt*2+1 (rows r0..r0+31)
  const short* qf = qf_ + ((size_t)(bh * 64 + rt * 2) << 10);
  bfx8 aq00 = *(const bfx8*)&qf[l * 8];
  bfx8 aq01 = *(const bfx8*)&qf[512 + l * 8];
  bfx8 aq10 = *(const bfx8*)&qf[1024 + l * 8];
  bfx8 aq11 = *(const bfx8*)&qf[1536 + l * 8];

  const unsigned char* mb = msk + b * 1024;
  const bool rowok0 = mb[r0 + lr] != 0;
  const bool rowok1 = mb[r0 + 16 + lr] != 0;

  // ---- phase 1: QK^T, sc[qb][cc] ----
  f32x4 sc[2][8];
  #pragma unroll
  for (int cc = 0; cc < 8; cc++) {
    const short* kfp = kf_ + ((size_t)(bh * 64 + w * 8 + cc) << 10);
    bfx8 bk0 = *(const bfx8*)&kfp[l * 8];
    bfx8 bk1 = *(const bfx8*)&kfp[512 + l * 8];
    f32x4 a0 = {}, a1 = {};
    a0 = __builtin_amdgcn_mfma_f32_16x16x32_bf16(bk0, aq00, a0, 0, 0, 0);
    a0 = __builtin_amdgcn_mfma_f32_16x16x32_bf16(bk1, aq01, a0, 0, 0, 0);
    a1 = __builtin_amdgcn_mfma_f32_16x16x32_bf16(bk0, aq10, a1, 0, 0, 0);
    a1 = __builtin_amdgcn_mfma_f32_16x16x32_bf16(bk1, aq11, a1, 0, 0, 0);
    unsigned cm = *(const unsigned*)&mb[w * 128 + cc * 16 + 4 * lk];
    #pragma unroll
    for (int i = 0; i < 4; i++) {
      bool cok = ((cm >> (8 * i)) & 0xffu) != 0u;
      sc[0][cc][i] = (cok && rowok0) ? a0[i] * 0.03125f : NEG;
      sc[1][cc][i] = (cok && rowok1) ? a1[i] * 0.03125f : NEG;
    }
  }

  // ---- phase 2: softmax per row (rows qb*16+lr) ----
  float m0r = NEG, m1r = NEG;
  #pragma unroll
  for (int f = 0; f < 8; f++)
    #pragma unroll
    for (int i = 0; i < 4; i++) {
      m0r = fmaxf(m0r, sc[0][f][i]);
      m1r = fmaxf(m1r, sc[1][f][i]);
    }
  m0r = fmaxf(m0r, __shfl_xor(m0r, 16)); m0r = fmaxf(m0r, __shfl_xor(m0r, 32));
  m1r = fmaxf(m1r, __shfl_xor(m1r, 16)); m1r = fmaxf(m1r, __shfl_xor(m1r, 32));
  if (lk == 0) { redM[lr][w] = m0r; redM[16 + lr][w] = m1r; }
  __syncthreads();
  {
    float4 a = *(const float4*)&redM[lr][0];
    float4 bq = *(const float4*)&redM[lr][4];
    m0r = fmaxf(fmaxf(fmaxf(a.x, a.y), fmaxf(a.z, a.w)),
                fmaxf(fmaxf(bq.x, bq.y), fmaxf(bq.z, bq.w)));
    float4 c = *(const float4*)&redM[16 + lr][0];
    float4 d = *(const float4*)&redM[16 + lr][4];
    m1r = fmaxf(fmaxf(fmaxf(c.x, c.y), fmaxf(c.z, c.w)),
                fmaxf(fmaxf(d.x, d.y), fmaxf(d.z, d.w)));
  }
  float s0 = 0.f, s1 = 0.f;
  #pragma unroll
  for (int f = 0; f < 8; f++)
    #pragma unroll
    for (int i = 0; i < 4; i++) {
      sc[0][f][i] = __expf(sc[0][f][i] - m0r); s0 += sc[0][f][i];
      sc[1][f][i] = __expf(sc[1][f][i] - m1r); s1 += sc[1][f][i];
    }
  s0 += __shfl_xor(s0, 16); s0 += __shfl_xor(s0, 32);
  s1 += __shfl_xor(s1, 16); s1 += __shfl_xor(s1, 32);
  if (lk == 0) { redS[lr][w] = s0; redS[16 + lr][w] = s1; }
  __syncthreads();
  float inv0, inv1;
  {
    float4 a = *(const float4*)&redS[lr][0];
    float4 bq = *(const float4*)&redS[lr][4];
    inv0 = 1.0f / (a.x + a.y + a.z + a.w + bq.x + bq.y + bq.z + bq.w);
    float4 c = *(const float4*)&redS[16 + lr][0];
    float4 d = *(const float4*)&redS[16 + lr][4];
    inv1 = 1.0f / (c.x + c.y + c.z + c.w + d.x + d.y + d.z + d.w);
  }

  // ---- P (bf16) -> LDS, swizzled: row qb*16+lr, col w*128 + cc*16 + 4lk ----
  #pragma unroll
  for (int qb = 0; qb < 2; qb++) {
    float invq = qb ? inv1 : inv0;
    int row = qb * 16 + lr;
    #pragma unroll
    for (int cc = 0; cc < 8; cc++) {
      union { ushort u[4]; uint2 d; } pk;
      pk.u[0] = (ushort)f2bfbits(sc[qb][cc][0] * invq);
      pk.u[1] = (ushort)f2bfbits(sc[qb][cc][1] * invq);
      pk.u[2] = (ushort)f2bfbits(sc[qb][cc][2] * invq);
      pk.u[3] = (ushort)f2bfbits(sc[qb][cc][3] * invq);
      int slot_lin = w * 16 + cc * 2 + (lk >> 1);
      int addr = row * 2048 + ((slot_lin ^ (row & 7)) << 4) + ((lk & 1) << 3);
      *(uint2*)((char*)P + addr) = pk.d;
    }
  }
  __syncthreads();   // P visible to all waves

  // ---- stream attn out NOW (overlaps PV below): 4 rows/wave, 1KB lines ----
  #pragma unroll
  for (int rg = 0; rg < 4; rg++) {
    int row = w * 4 + rg;
    float* arow = attn + ((size_t)bh * 1024 + r0 + row) * 1024;
    int swr = row & 7;
    #pragma unroll
    for (int it = 0; it < 4; it++) {
      int ci = it * 64 + l;              // 16B output chunk (4 f32)
      uint2 d = *(const uint2*)((const char*)P + row * 2048 +
                                (((ci >> 1) ^ swr) << 4) + ((ci & 1) << 3));
      float4 o;
      o.x = __uint_as_float(d.x << 16);
      o.y = __uint_as_float(d.x & 0xffff0000u);
      o.z = __uint_as_float(d.y << 16);
      o.w = __uint_as_float(d.y & 0xffff0000u);
      *(float4*)&arow[ci * 4] = o;
    }
  }

  // ---- phase 3: ctx = P @ V; wave w: row-block rb=w>>2, dim-grp dg=w&3 ----
  const int dg = w & 3, rb = w >> 2;
  const int prow = rb * 16 + lr;
  const int psw = lr & 7;                 // (rb*16+lr)&7 == lr&7
  f32x4 o0 = {}, o1 = {};
  #pragma unroll
  for (int jj = 0; jj < 32; jj++) {
    const short* vfp = vf_ + (((size_t)(bh * 4 + dg) * 32 + jj) << 9);
    bfx8 bv = *(const bfx8*)&vfp[l * 8];
    int slot_lin = jj * 4 + lk;
    bfx8 pa = *(const bfx8*)((const char*)P + prow * 2048 +
                             ((slot_lin ^ psw) << 4));
    if (jj & 1) o1 = __builtin_amdgcn_mfma_f32_16x16x32_bf16(pa, bv, o1, 0, 0, 0);
    else        o0 = __builtin_amdgcn_mfma_f32_16x16x32_bf16(pa, bv, o0, 0, 0, 0);
  }
  #pragma unroll
  for (int i = 0; i < 4; i++) {
    float v = o0[i] + o1[i];
    ctx[(((size_t)b << 10) + r0 + rb * 16 + 4 * lk + i) * 1024 +
        (h << 6) + (dg << 4) + lr] = f2bfbits(v);
  }
}

// ---------------- launch ----------------

extern "C" void kernel_launch(void* const* d_in, const int* in_sizes, int n_in,
                              void* d_out, int out_size, void* d_ws, size_t ws_size,
                              hipStream_t stream) {
  const float* x    = (const float*)d_in[0];
  const int*   mask = (const int*)d_in[1];
  const float* Wqkv = (const float*)d_in[2];
  const float* bqkv = (const float*)d_in[3];
  const float* Wout = (const float*)d_in[4];
  const float* bout = (const float*)d_in[5];
  float* out  = (float*)d_out;
  float* attn = out + (size_t)4 * 1024 * 1024;

  char* ws = (char*)d_ws;
  short* xb    = (short*)(ws);                  //  8 MB  x bf16 [4096][1024]
  short* wqkvT = (short*)(ws + 8388608);        //  6 MB  [3072][1024]
  short* woutT = (short*)(ws + 14680064);       //  2 MB  [1024][1024]
  short* qfr   = (short*)(ws + 16777216);       //  8 MB  Q fragments
  short* kfr   = (short*)(ws + 25165824);       //  8 MB  K fragments
  short* vfr   = (short*)(ws + 33554432);       //  8 MB  V fragments
  short* ctx   = (short*)(ws + 41943040);       //  8 MB  [4096][1024]
  unsigned char* msk = (unsigned char*)(ws + 50331648);  // 4 KB

  k_prep<<<8208, 256, 0, stream>>>(x, xb, mask, msk, Wqkv, wqkvT, Wout, woutT);
  k_gemm<<<dim3(24, 32), 256, 0, stream>>>(xb, wqkvT, bqkv, 1024, qfr, kfr, vfr);
  k_attn<<<2048, 512, 0, stream>>>(qfr, kfr, vfr, msk, attn, ctx);
  k_gemm_out<<<dim3(16, 32), 256, 0, stream>>>(ctx, woutT, bout, out);
}

// Round 10
// 142.807 us; speedup vs baseline: 1.0140x; 1.0140x over previous
//
#include <hip/hip_runtime.h>
#include <stdint.h>

#define DEV static __device__ __forceinline__

typedef __attribute__((ext_vector_type(8))) __bf16 bfx8;
typedef __attribute__((ext_vector_type(4))) float f32x4;

DEV short f2bfbits(float f) {
  union { float f; unsigned u; } v; v.f = f;
  unsigned r = v.u + 0x7fffu + ((v.u >> 16) & 1u);
  return (short)(r >> 16);
}

DEV void gload_lds16(const void* g, void* lds) {
  __builtin_amdgcn_global_load_lds(
      (const __attribute__((address_space(1))) void*)g,
      (__attribute__((address_space(3))) void*)lds, 16, 0, 0);
}

// ---------------- prep (merged): x->bf16 | mask | both weight transposes ----------------
__global__ void k_prep(const float* __restrict__ x, short* __restrict__ xb,
                       const int* __restrict__ mask, unsigned char* __restrict__ msk,
                       const float* __restrict__ Wqkv, short* __restrict__ wqkvT,
                       const float* __restrict__ Wout, short* __restrict__ woutT) {
  __shared__ float tile[32][33];
  int bx = blockIdx.x;
  int t = threadIdx.x;
  if (bx < 4096) {
    int i = bx * 256 + t;                            // 4 floats per thread
    float4 v = ((const float4*)x)[i];
    union { short s[4]; uint64_t u; } o;
    o.s[0] = f2bfbits(v.x); o.s[1] = f2bfbits(v.y);
    o.s[2] = f2bfbits(v.z); o.s[3] = f2bfbits(v.w);
    ((uint64_t*)xb)[i] = o.u;
  } else if (bx < 4112) {
    int i = (bx - 4096) * 256 + t;                   // [0, 4096)
    int b = i >> 10, n = i & 1023;
    msk[i] = (n == 0) ? (unsigned char)1 : (unsigned char)(mask[b * 1023 + n - 1] != 0);
  } else {
    int tb = bx - 4112;                              // 4096 transpose blocks
    int bxx = tb & 127, byy = tb >> 7;
    const float* src; short* dst; int C;
    if (bxx < 96) { src = Wqkv; dst = wqkvT; C = 3072; }
    else          { src = Wout; dst = woutT; C = 1024; bxx -= 96; }
    const int R = 1024;
    int c0 = bxx * 32, r0 = byy * 32;
    int tx = t & 31, ty = t >> 5;                    // (32,8)
    #pragma unroll
    for (int j = 0; j < 32; j += 8)
      tile[ty + j][tx] = src[(size_t)(r0 + ty + j) * C + c0 + tx];
    __syncthreads();
    #pragma unroll
    for (int j = 0; j < 32; j += 8)
      dst[(size_t)(c0 + ty + j) * R + r0 + tx] = f2bfbits(tile[tx][ty + j]);
  }
}

// ---------------- QKV GEMM: C = A[M][K] @ Bt[N][K]^T + bias -> fragment layouts ----
//   q/kfrag: [bh][blk=n>>4][half=d>>5][lane=((d>>3)&3)*16+(n&15)][8]   (2KB per blk)
//   vfrag:   [bh][db=d>>4][jj=n>>5][lane=((n>>3)&3)*16+(d&15)][8]      (1KB per jj)
__global__ __launch_bounds__(256)
void k_gemm(const short* __restrict__ A, const short* __restrict__ Bt,
            const float* __restrict__ bias, int K,
            short* __restrict__ qf, short* __restrict__ kf,
            short* __restrict__ vf) {
  __shared__ short smem[8192];        // 16KB: staging As|Bs, then epilogue image
  short* As = smem;
  short* Bs = smem + 4096;
  const int t = threadIdx.x;
  const int l = t & 63, w = t >> 6;
  const int lr = l & 15, lk = l >> 4;
  const int m0 = blockIdx.y * 128, n0 = blockIdx.x * 128;
  const int wr = (w >> 1) * 64, wc = (w & 1) * 64;
  f32x4 acc[4][4] = {};

  const int srow = t >> 2;
  const int sc8 = (t & 3) * 8;
  const size_t aoff1 = (size_t)(m0 + srow) * K + sc8;
  const size_t aoff2 = (size_t)(m0 + srow + 64) * K + sc8;
  const size_t boff1 = (size_t)(n0 + srow) * K + sc8;
  const size_t boff2 = (size_t)(n0 + srow + 64) * K + sc8;
  short* asd1 = As + (t & ~63) * 8;
  short* asd2 = As + (t & ~63) * 8 + 2048;
  short* bsd1 = Bs + (t & ~63) * 8;
  short* bsd2 = Bs + (t & ~63) * 8 + 2048;

  for (int k0 = 0; k0 < K; k0 += 32) {
    gload_lds16(A + aoff1 + k0, asd1);
    gload_lds16(A + aoff2 + k0, asd2);
    gload_lds16(Bt + boff1 + k0, bsd1);
    gload_lds16(Bt + boff2 + k0, bsd2);
    __syncthreads();
    bfx8 af[4], bf[4];
    #pragma unroll
    for (int m = 0; m < 4; m++)
      af[m] = *(const bfx8*)&As[(wr + m * 16 + lr) * 32 + lk * 8];
    #pragma unroll
    for (int n = 0; n < 4; n++)
      bf[n] = *(const bfx8*)&Bs[(wc + n * 16 + lr) * 32 + lk * 8];
    #pragma unroll
    for (int m = 0; m < 4; m++)
      #pragma unroll
      for (int n = 0; n < 4; n++)
        acc[m][n] = __builtin_amdgcn_mfma_f32_16x16x32_bf16(af[m], bf[n], acc[m][n], 0, 0, 0);
    __syncthreads();
  }

  // ---- epilogue: fragment-ordered LDS image, then coalesced stores ----
  const int which = n0 >> 10;                 // 0=q 1=k 2=v (tiles never straddle)
  const int head = w & 1;                     // head within the 128-col tile
  const int band = w >> 1;                    // row band (wr/64)
  const int bb = m0 >> 10;
  short* dstp = (which == 0) ? qf : (which == 1) ? kf : vf;

  #pragma unroll
  for (int p = 0; p < 2; p++) {
    #pragma unroll
    for (int mm = 0; mm < 2; mm++) {
      int m = 2 * p + mm;
      #pragma unroll
      for (int n = 0; n < 4; n++) {
        int gc = n0 + wc + n * 16 + lr;
        float bv = bias[gc];
        #pragma unroll
        for (int i = 0; i < 4; i++) {
          short val = f2bfbits(acc[m][n][i] + bv);
          int off;
          if (which < 2) {
            off = ((((band * 2 + head) * 2 + mm) * 2 + (n >> 1)) * 64 +
                   ((2 * n + (lr >> 3)) & 3) * 16 + 4 * lk + i) * 8 + (lr & 7);
          } else {
            off = (((band * 2 + head) * 4 + n) * 64 +
                   (2 * mm + ((4 * lk + i) >> 3)) * 16 + lr) * 8 + ((4 * lk + i) & 7);
          }
          smem[off] = val;
        }
      }
    }
    __syncthreads();
    if (which < 2) {
      #pragma unroll
      for (int r = 0; r < 4; r++) {
        int rb = r >> 1, rh = r & 1;
        int bh_r = bb * 16 + ((n0 & 1023) >> 6) + rh;
        int blk0 = ((m0 & 1023) >> 4) + 4 * rb + 2 * p;
        size_t g = ((size_t)(bh_r * 64 + blk0) << 10) + t * 8;
        *(int4*)&dstp[g] = *(const int4*)&smem[r * 2048 + t * 8];
      }
    } else {
      #pragma unroll
      for (int r = 0; r < 4; r++) {
        int rb = r >> 1, rh = r & 1;
        int bh_r = bb * 16 + ((n0 & 1023) >> 6) + rh;
        int jj = ((m0 & 1023) >> 5) + 2 * rb + p;
        int db = t >> 6;
        size_t g = (((size_t)(bh_r * 4 + db) * 32 + jj) << 9) + (t & 63) * 8;
        *(int4*)&dstp[g] = *(const int4*)&smem[r * 2048 + t * 8];
      }
    }
    if (p == 0) __syncthreads();
  }
}

// ---------------- out GEMM: BM=128, BN=64 -> 512 WGs (2/CU) ----------------
__global__ __launch_bounds__(256)
void k_gemm_out(const short* __restrict__ A, const short* __restrict__ Bt,
                const float* __restrict__ bias, float* __restrict__ outF) {
  __shared__ short As[128 * 32];
  __shared__ short Bs[64 * 32];
  const int K = 1024;
  const int t = threadIdx.x;
  const int l = t & 63, w = t >> 6;
  const int lr = l & 15, lk = l >> 4;
  const int m0 = blockIdx.y * 128, n0 = blockIdx.x * 64;
  const int wr = (w >> 1) * 64, wc = (w & 1) * 32;
  f32x4 acc[4][2] = {};

  const int srow = t >> 2;
  const int sc8 = (t & 3) * 8;
  const size_t aoff1 = (size_t)(m0 + srow) * K + sc8;
  const size_t aoff2 = (size_t)(m0 + srow + 64) * K + sc8;
  const size_t boff1 = (size_t)(n0 + srow) * K + sc8;
  short* asd1 = As + (t & ~63) * 8;
  short* asd2 = As + (t & ~63) * 8 + 2048;
  short* bsd1 = Bs + (t & ~63) * 8;

  for (int k0 = 0; k0 < K; k0 += 32) {
    gload_lds16(A + aoff1 + k0, asd1);
    gload_lds16(A + aoff2 + k0, asd2);
    gload_lds16(Bt + boff1 + k0, bsd1);
    __syncthreads();
    bfx8 af[4], bf[2];
    #pragma unroll
    for (int m = 0; m < 4; m++)
      af[m] = *(const bfx8*)&As[(wr + m * 16 + lr) * 32 + lk * 8];
    #pragma unroll
    for (int n = 0; n < 2; n++)
      bf[n] = *(const bfx8*)&Bs[(wc + n * 16 + lr) * 32 + lk * 8];
    #pragma unroll
    for (int m = 0; m < 4; m++)
      #pragma unroll
      for (int n = 0; n < 2; n++)
        acc[m][n] = __builtin_amdgcn_mfma_f32_16x16x32_bf16(af[m], bf[n], acc[m][n], 0, 0, 0);
    __syncthreads();
  }

  #pragma unroll
  for (int m = 0; m < 4; m++) {
    #pragma unroll
    for (int n = 0; n < 2; n++) {
      int gc = n0 + wc + n * 16 + lr;
      float bv = bias[gc];
      #pragma unroll
      for (int i = 0; i < 4; i++) {
        int gr = m0 + wr + m * 16 + 4 * lk + i;
        outF[(size_t)gr * 1024 + gc] = acc[m][n][i] + bv;
      }
    }
  }
}

// ---------------- fused attention v6: QBLK=32, 2048 WGs ----------------
__global__ __launch_bounds__(512, 2)
void k_attn(const short* __restrict__ qf_, const short* __restrict__ kf_,
            const short* __restrict__ vf_, const unsigned char* __restrict__ msk,
            float* __restrict__ attn, short* __restrict__ ctx) {
  __shared__ short P[32 * 1024];      // 64KB bf16 P, swizzled 16B slots
  __shared__ float redM[32][8];
  __shared__ float redS[32][8];
  const int t = threadIdx.x, l = t & 63, w = t >> 6;
  const int lr = l & 15, lk = l >> 4;
  // XCD-chunked swizzle: 2048 WGs = 8 XCDs x 256; 32 consecutive = one (b,h)
  const int wg = ((blockIdx.x & 7) << 8) | (blockIdx.x >> 3);
  const int rt = wg & 31, h = (wg >> 5) & 15, b = wg >> 9;
  const int bh = b * 16 + h;
  const int r0 = rt * 32;
  const float NEG = -3.402823466e38f;

  // Q fragments: blocks rt*2, rt*2+1 (rows r0..r0+31)
  const short* qf = qf_ + ((size_t)(bh * 64 + rt * 2) << 10);
  bfx8 aq00 = *(const bfx8*)&qf[l * 8];
  bfx8 aq01 = *(const bfx8*)&qf[512 + l * 8];
  bfx8 aq10 = *(const bfx8*)&qf[1024 + l * 8];
  bfx8 aq11 = *(const bfx8*)&qf[1536 + l * 8];

  const unsigned char* mb = msk + b * 1024;
  const bool rowok0 = mb[r0 + lr] != 0;
  const bool rowok1 = mb[r0 + 16 + lr] != 0;

  // ---- phase 1: QK^T, sc[qb][cc] ----
  f32x4 sc[2][8];
  #pragma unroll
  for (int cc = 0; cc < 8; cc++) {
    const short* kfp = kf_ + ((size_t)(bh * 64 + w * 8 + cc) << 10);
    bfx8 bk0 = *(const bfx8*)&kfp[l * 8];
    bfx8 bk1 = *(const bfx8*)&kfp[512 + l * 8];
    f32x4 a0 = {}, a1 = {};
    a0 = __builtin_amdgcn_mfma_f32_16x16x32_bf16(bk0, aq00, a0, 0, 0, 0);
    a0 = __builtin_amdgcn_mfma_f32_16x16x32_bf16(bk1, aq01, a0, 0, 0, 0);
    a1 = __builtin_amdgcn_mfma_f32_16x16x32_bf16(bk0, aq10, a1, 0, 0, 0);
    a1 = __builtin_amdgcn_mfma_f32_16x16x32_bf16(bk1, aq11, a1, 0, 0, 0);
    unsigned cm = *(const unsigned*)&mb[w * 128 + cc * 16 + 4 * lk];
    #pragma unroll
    for (int i = 0; i < 4; i++) {
      bool cok = ((cm >> (8 * i)) & 0xffu) != 0u;
      sc[0][cc][i] = (cok && rowok0) ? a0[i] * 0.03125f : NEG;
      sc[1][cc][i] = (cok && rowok1) ? a1[i] * 0.03125f : NEG;
    }
  }

  // ---- phase 2: softmax per row (rows qb*16+lr) ----
  float m0r = NEG, m1r = NEG;
  #pragma unroll
  for (int f = 0; f < 8; f++)
    #pragma unroll
    for (int i = 0; i < 4; i++) {
      m0r = fmaxf(m0r, sc[0][f][i]);
      m1r = fmaxf(m1r, sc[1][f][i]);
    }
  m0r = fmaxf(m0r, __shfl_xor(m0r, 16)); m0r = fmaxf(m0r, __shfl_xor(m0r, 32));
  m1r = fmaxf(m1r, __shfl_xor(m1r, 16)); m1r = fmaxf(m1r, __shfl_xor(m1r, 32));
  if (lk == 0) { redM[lr][w] = m0r; redM[16 + lr][w] = m1r; }
  __syncthreads();
  {
    float4 a = *(const float4*)&redM[lr][0];
    float4 bq = *(const float4*)&redM[lr][4];
    m0r = fmaxf(fmaxf(fmaxf(a.x, a.y), fmaxf(a.z, a.w)),
                fmaxf(fmaxf(bq.x, bq.y), fmaxf(bq.z, bq.w)));
    float4 c = *(const float4*)&redM[16 + lr][0];
    float4 d = *(const float4*)&redM[16 + lr][4];
    m1r = fmaxf(fmaxf(fmaxf(c.x, c.y), fmaxf(c.z, c.w)),
                fmaxf(fmaxf(d.x, d.y), fmaxf(d.z, d.w)));
  }
  float s0 = 0.f, s1 = 0.f;
  #pragma unroll
  for (int f = 0; f < 8; f++)
    #pragma unroll
    for (int i = 0; i < 4; i++) {
      sc[0][f][i] = __expf(sc[0][f][i] - m0r); s0 += sc[0][f][i];
      sc[1][f][i] = __expf(sc[1][f][i] - m1r); s1 += sc[1][f][i];
    }
  s0 += __shfl_xor(s0, 16); s0 += __shfl_xor(s0, 32);
  s1 += __shfl_xor(s1, 16); s1 += __shfl_xor(s1, 32);
  if (lk == 0) { redS[lr][w] = s0; redS[16 + lr][w] = s1; }
  __syncthreads();
  float inv0, inv1;
  {
    float4 a = *(const float4*)&redS[lr][0];
    float4 bq = *(const float4*)&redS[lr][4];
    inv0 = 1.0f / (a.x + a.y + a.z + a.w + bq.x + bq.y + bq.z + bq.w);
    float4 c = *(const float4*)&redS[16 + lr][0];
    float4 d = *(const float4*)&redS[16 + lr][4];
    inv1 = 1.0f / (c.x + c.y + c.z + c.w + d.x + d.y + d.z + d.w);
  }

  // ---- P (bf16) -> LDS, swizzled: row qb*16+lr, col w*128 + cc*16 + 4lk ----
  #pragma unroll
  for (int qb = 0; qb < 2; qb++) {
    float invq = qb ? inv1 : inv0;
    int row = qb * 16 + lr;
    #pragma unroll
    for (int cc = 0; cc < 8; cc++) {
      union { ushort u[4]; uint2 d; } pk;
      pk.u[0] = (ushort)f2bfbits(sc[qb][cc][0] * invq);
      pk.u[1] = (ushort)f2bfbits(sc[qb][cc][1] * invq);
      pk.u[2] = (ushort)f2bfbits(sc[qb][cc][2] * invq);
      pk.u[3] = (ushort)f2bfbits(sc[qb][cc][3] * invq);
      int slot_lin = w * 16 + cc * 2 + (lk >> 1);
      int addr = row * 2048 + ((slot_lin ^ (row & 7)) << 4) + ((lk & 1) << 3);
      *(uint2*)((char*)P + addr) = pk.d;
    }
  }
  __syncthreads();   // P visible to all waves

  // ---- stream attn out NOW (overlaps PV below): 4 rows/wave, 1KB lines ----
  #pragma unroll
  for (int rg = 0; rg < 4; rg++) {
    int row = w * 4 + rg;
    float* arow = attn + ((size_t)bh * 1024 + r0 + row) * 1024;
    int swr = row & 7;
    #pragma unroll
    for (int it = 0; it < 4; it++) {
      int ci = it * 64 + l;              // 16B output chunk (4 f32)
      uint2 d = *(const uint2*)((const char*)P + row * 2048 +
                                (((ci >> 1) ^ swr) << 4) + ((ci & 1) << 3));
      float4 o;
      o.x = __uint_as_float(d.x << 16);
      o.y = __uint_as_float(d.x & 0xffff0000u);
      o.z = __uint_as_float(d.y << 16);
      o.w = __uint_as_float(d.y & 0xffff0000u);
      *(float4*)&arow[ci * 4] = o;
    }
  }

  // ---- phase 3: ctx = P @ V; wave w: row-block rb=w>>2, dim-grp dg=w&3 ----
  const int dg = w & 3, rb = w >> 2;
  const int prow = rb * 16 + lr;
  const int psw = lr & 7;                 // (rb*16+lr)&7 == lr&7
  f32x4 o0 = {}, o1 = {};
  #pragma unroll
  for (int jj = 0; jj < 32; jj++) {
    const short* vfp = vf_ + (((size_t)(bh * 4 + dg) * 32 + jj) << 9);
    bfx8 bv = *(const bfx8*)&vfp[l * 8];
    int slot_lin = jj * 4 + lk;
    bfx8 pa = *(const bfx8*)((const char*)P + prow * 2048 +
                             ((slot_lin ^ psw) << 4));
    if (jj & 1) o1 = __builtin_amdgcn_mfma_f32_16x16x32_bf16(pa, bv, o1, 0, 0, 0);
    else        o0 = __builtin_amdgcn_mfma_f32_16x16x32_bf16(pa, bv, o0, 0, 0, 0);
  }
  #pragma unroll
  for (int i = 0; i < 4; i++) {
    float v = o0[i] + o1[i];
    ctx[(((size_t)b << 10) + r0 + rb * 16 + 4 * lk + i) * 1024 +
        (h << 6) + (dg << 4) + lr] = f2bfbits(v);
  }
}

// ---------------- launch ----------------

extern "C" void kernel_launch(void* const* d_in, const int* in_sizes, int n_in,
                              void* d_out, int out_size, void* d_ws, size_t ws_size,
                              hipStream_t stream) {
  const float* x    = (const float*)d_in[0];
  const int*   mask = (const int*)d_in[1];
  const float* Wqkv = (const float*)d_in[2];
  const float* bqkv = (const float*)d_in[3];
  const float* Wout = (const float*)d_in[4];
  const float* bout = (const float*)d_in[5];
  float* out  = (float*)d_out;
  float* attn = out + (size_t)4 * 1024 * 1024;

  char* ws = (char*)d_ws;
  short* xb    = (short*)(ws);                  //  8 MB  x bf16 [4096][1024]
  short* wqkvT = (short*)(ws + 8388608);        //  6 MB  [3072][1024]
  short* woutT = (short*)(ws + 14680064);       //  2 MB  [1024][1024]
  short* qfr   = (short*)(ws + 16777216);       //  8 MB  Q fragments
  short* kfr   = (short*)(ws + 25165824);       //  8 MB  K fragments
  short* vfr   = (short*)(ws + 33554432);       //  8 MB  V fragments
  short* ctx   = (short*)(ws + 41943040);       //  8 MB  [4096][1024]
  unsigned char* msk = (unsigned char*)(ws + 50331648);  // 4 KB

  k_prep<<<8208, 256, 0, stream>>>(x, xb, mask, msk, Wqkv, wqkvT, Wout, woutT);
  k_gemm<<<dim3(24, 32), 256, 0, stream>>>(xb, wqkvT, bqkv, 1024, qfr, kfr, vfr);
  k_attn<<<2048, 512, 0, stream>>>(qfr, kfr, vfr, msk, attn, ctx);
  k_gemm_out<<<dim3(16, 32), 256, 0, stream>>>(ctx, woutT, bout, out);
}